// Round 7
// baseline (366.205 us; speedup 1.0000x reference)
//
#include <hip/hip_runtime.h>
#include <hip/hip_bf16.h>

#define D_MODEL   1024
#define D_STATE   64
#define D_INNER   2048
#define NHEADS    32
#define CONV_DIM  2176
#define D_IN_PROJ 4256
#define NPAD      4352
#define BATCH     8
#define SEQ       1024
#define NROWS     8192
#define NCHUNK    8
#define CLEN      128

typedef __attribute__((ext_vector_type(8))) short bf16x8;
typedef __attribute__((ext_vector_type(4))) float f32x4;

__device__ __forceinline__ float bf2f(unsigned short u){
  unsigned v = ((unsigned)u) << 16;
  return __builtin_bit_cast(float, v);
}
__device__ __forceinline__ unsigned short f2bf(float f){
  __hip_bfloat16 h = __float2bfloat16(f);
  return __builtin_bit_cast(unsigned short, h);
}

// conv+silu for 8 channels (xBC-channel base cc, within-batch pos l, batch b)
__device__ __forceinline__ void conv8(const unsigned short* __restrict__ zx,
                                      const float* __restrict__ conv_w,
                                      const float* __restrict__ conv_b,
                                      int b, int l, int cc, float* o){
  float acc[8];
  #pragma unroll
  for (int j = 0; j < 8; ++j) acc[j] = conv_b[cc + j];
  #pragma unroll
  for (int k = 0; k < 4; ++k){
    int lr = l + k - 3;
    if (lr >= 0){
      bf16x8 v = *(const bf16x8*)(zx + (size_t)(b*SEQ + lr)*NPAD + 2048 + cc);
      #pragma unroll
      for (int j = 0; j < 8; ++j)
        acc[j] = fmaf(bf2f((unsigned short)v[j]), conv_w[k*CONV_DIM + cc + j], acc[j]);
    }
  }
  #pragma unroll
  for (int j = 0; j < 8; ++j) o[j] = acc[j] / (1.f + expf(-acc[j]));
}

// ---------------- convert x (fp32 -> bf16) ----------------
__global__ __launch_bounds__(256) void k_convert_x(const float* __restrict__ x,
                                                   unsigned short* __restrict__ xb){
  int i = blockIdx.x*256 + threadIdx.x;
  float4 v = ((const float4*)x)[i];
  ushort4 o;
  o.x = f2bf(v.x); o.y = f2bf(v.y); o.z = f2bf(v.z); o.w = f2bf(v.w);
  ((ushort4*)xb)[i] = o;
}

// ---------------- transpose W_in [K][N] -> bf16 [NPAD][K] -------------------
__global__ __launch_bounds__(256) void k_transpose_win(const float* __restrict__ W_in,
                                                       unsigned short* __restrict__ wt){
  __shared__ float tile[32][33];
  int n0 = blockIdx.x * 32;
  int k0 = blockIdx.y * 32;
  int tx = threadIdx.x & 31;
  int ty = threadIdx.x >> 5;
  #pragma unroll
  for (int i = 0; i < 4; ++i){
    int kk = ty + i*8;
    int n  = n0 + tx;
    tile[kk][tx] = (n < D_IN_PROJ) ? W_in[(size_t)(k0+kk)*D_IN_PROJ + n] : 0.f;
  }
  __syncthreads();
  #pragma unroll
  for (int i = 0; i < 4; ++i){
    int nn = ty + i*8;
    wt[(size_t)(n0+nn)*D_MODEL + k0 + tx] = f2bf(tile[tx][nn]);
  }
}

// ---------------- nwc[d] = norm_w[d] * sum_k W_out[d][k]*head_w[k] ----------
__global__ __launch_bounds__(256) void k_nwc(const float* __restrict__ W_out,
                                             const float* __restrict__ head_w,
                                             const float* __restrict__ norm_w,
                                             float* __restrict__ nwc){
  int d    = blockIdx.x*4 + (threadIdx.x >> 6);
  int lane = threadIdx.x & 63;
  const float* row = W_out + (size_t)d * D_MODEL;
  float s = 0.f;
  #pragma unroll
  for (int k = lane; k < D_MODEL; k += 64) s += row[k] * head_w[k];
  #pragma unroll
  for (int off = 32; off; off >>= 1) s += __shfl_down(s, off);
  if (lane == 0) nwc[d] = s * norm_w[d];
}

// ---------------- bf16 MFMA GEMM with XCD-aware block swizzle ---------------
__global__ __launch_bounds__(256) void k_gemm_bf16_bt(const unsigned short* __restrict__ A,
                                                      const unsigned short* __restrict__ BT,
                                                      unsigned short* __restrict__ C,
                                                      int M, int N, int K){
  __shared__ unsigned short aT[128*64];
  __shared__ unsigned short bT[128*64];
  int nb   = N >> 7;
  // XCD swizzle (grid % 8 == 0): XCD k owns a contiguous logical chunk
  int bid  = blockIdx.x;
  int swz  = (bid & 7) * (gridDim.x >> 3) + (bid >> 3);
  int m0   = (swz / nb) << 7;
  int n0   = (swz % nb) << 7;
  int tid  = threadIdx.x;
  int wid  = tid >> 6, lane = tid & 63;
  int wr   = wid >> 1, wc = wid & 1;

  f32x4 acc[4][4];
  #pragma unroll
  for (int i = 0; i < 4; ++i)
    #pragma unroll
    for (int j = 0; j < 4; ++j)
      acc[i][j] = (f32x4){0.f, 0.f, 0.f, 0.f};

  int frow = lane & 15;
  int fk   = (lane >> 4) << 3;
  int srow = lane >> 3;
  int skk  = (lane & 7) << 3;

  for (int k0 = 0; k0 < K; k0 += 64){
    __syncthreads();
    #pragma unroll
    for (int it = 0; it < 4; ++it){
      int ch  = (wid << 2) | it;
      int row = (ch << 3) | srow;
      __builtin_amdgcn_global_load_lds(
        (const __attribute__((address_space(1))) void*)(A  + (size_t)(m0+row)*K + k0 + skk),
        (__attribute__((address_space(3))) void*)(aT + (ch << 9)), 16, 0, 0);
      __builtin_amdgcn_global_load_lds(
        (const __attribute__((address_space(1))) void*)(BT + (size_t)(n0+row)*K + k0 + skk),
        (__attribute__((address_space(3))) void*)(bT + (ch << 9)), 16, 0, 0);
    }
    __syncthreads();
    #pragma unroll
    for (int kk = 0; kk < 64; kk += 32){
      bf16x8 af[4], bfv[4];
      #pragma unroll
      for (int i = 0; i < 4; ++i)
        af[i]  = *(const bf16x8*)(aT + ((wr*64 + i*16 + frow) << 6) + kk + fk);
      #pragma unroll
      for (int j = 0; j < 4; ++j)
        bfv[j] = *(const bf16x8*)(bT + ((wc*64 + j*16 + frow) << 6) + kk + fk);
      #pragma unroll
      for (int i = 0; i < 4; ++i)
        #pragma unroll
        for (int j = 0; j < 4; ++j)
          acc[i][j] = __builtin_amdgcn_mfma_f32_16x16x32_bf16(af[i], bfv[j], acc[i][j], 0, 0, 0);
    }
  }

  int crow = (lane >> 4) << 2;
  int ccol = lane & 15;
  #pragma unroll
  for (int i = 0; i < 4; ++i)
    #pragma unroll
    for (int j = 0; j < 4; ++j){
      size_t base = (size_t)(m0 + wr*64 + i*16 + crow) * N + (n0 + wc*64 + j*16 + ccol);
      #pragma unroll
      for (int r = 0; r < 4; ++r)
        C[base + (size_t)r * N] = f2bf(acc[i][j][r]);
    }
}

// ---------------- dt = softplus(raw + bias), transposed [bh][t] -------------
__global__ __launch_bounds__(256) void k_dtda(const unsigned short* __restrict__ zx,
                                              const float* __restrict__ dt_bias,
                                              float* __restrict__ dtb){
  int i = blockIdx.x*256 + threadIdx.x;
  int r = i >> 5, h = i & 31;
  float raw = bf2f(zx[(size_t)r*NPAD + D_INNER + CONV_DIM + h]) + dt_bias[h];
  float dt  = (raw > 20.f) ? raw : log1pf(expf(raw));
  int b = r >> 10, l = r & 1023;
  dtb[(b*32 + h)*1024 + l] = dt;
}

// ---------------- per-chunk inclusive cumsum of dt + cumA -------------------
__global__ __launch_bounds__(64) void k_cs(const float* __restrict__ dtb,
                                           const float* __restrict__ A_log,
                                           float* __restrict__ csb,
                                           float* __restrict__ cumA){
  int id = blockIdx.x;                 // bh*8 + c
  int bh = id >> 3, c = id & 7;
  int h  = bh & 31;
  int l  = threadIdx.x;
  const float* src = dtb + (size_t)bh*1024 + (c << 7);
  float d0 = src[2*l], d1 = src[2*l + 1];
  float pr = d0 + d1;
  float s  = pr;
  #pragma unroll
  for (int off = 1; off < 64; off <<= 1){
    float n = __shfl_up(s, off);
    if (l >= off) s += n;
  }
  float excl = s - pr;
  csb[(size_t)id*128 + 2*l]     = excl + d0;
  csb[(size_t)id*128 + 2*l + 1] = excl + pr;
  if (l == 63){
    float A = -expf(A_log[h]);
    cumA[id] = expf(A * s);
  }
}

// ---------------- SSD pass 1 (conv fused): h_end = (w*X)^T @ B --------------
__global__ __launch_bounds__(256) void k_ssd1(const unsigned short* __restrict__ zx,
                                              const float* __restrict__ conv_w,
                                              const float* __restrict__ conv_b,
                                              const float* __restrict__ dtb,
                                              const float* __restrict__ csb,
                                              const float* __restrict__ A_log,
                                              unsigned short* __restrict__ hend){
  __shared__ __align__(16) unsigned short XTw[64*136];
  __shared__ __align__(16) unsigned short BTl[64*136];
  int id = blockIdx.x;
  int bh = id >> 3, c = id & 7;
  int b  = bh >> 5, h = bh & 31;
  int tid = threadIdx.x;
  int w = tid >> 6, l = tid & 63;
  float A = -expf(A_log[h]);
  float csT = csb[(size_t)id*128 + 127];

  int pb = tid & 7, trow = tid >> 3;     // lane's channel-octet fixed across its
  int xcc = h*64 + pb*8;                 // x channels
  int bcc = 2048 + pb*8;                 // B channels
  #pragma unroll
  for (int it = 0; it < 4; ++it){
    int tau = trow + it*32;
    int lpos = (c << 7) + tau;
    float o[8];
    conv8(zx, conv_w, conv_b, b, lpos, xcc, o);
    float wgt = dtb[(size_t)bh*1024 + lpos]
              * expf(A*(csT - csb[(size_t)id*128 + tau]));
    #pragma unroll
    for (int j = 0; j < 8; ++j)
      XTw[(pb*8+j)*136 + tau] = f2bf(o[j] * wgt);
  }
  #pragma unroll
  for (int it = 0; it < 4; ++it){
    int tau = trow + it*32;
    int lpos = (c << 7) + tau;
    float o[8];
    conv8(zx, conv_w, conv_b, b, lpos, bcc, o);
    #pragma unroll
    for (int j = 0; j < 8; ++j)
      BTl[(pb*8+j)*136 + tau] = f2bf(o[j]);
  }
  __syncthreads();

  int fr = l & 15, fo = (l >> 4) << 3;
  f32x4 acc[4];
  #pragma unroll
  for (int n = 0; n < 4; ++n) acc[n] = (f32x4){0.f,0.f,0.f,0.f};
  #pragma unroll
  for (int kt = 0; kt < 4; ++kt){
    bf16x8 pf = *(const bf16x8*)(XTw + (w*16+fr)*136 + kt*32 + fo);
    #pragma unroll
    for (int n = 0; n < 4; ++n){
      bf16x8 qf = *(const bf16x8*)(BTl + (n*16+fr)*136 + kt*32 + fo);
      acc[n] = __builtin_amdgcn_mfma_f32_16x16x32_bf16(pf, qf, acc[n], 0, 0, 0);
    }
  }
  #pragma unroll
  for (int n = 0; n < 4; ++n)
    #pragma unroll
    for (int r = 0; r < 4; ++r){
      int p = w*16 + ((l>>4)<<2) + r;
      int s = n*16 + fr;
      hend[(size_t)id*4096 + p*64 + s] = f2bf(acc[n][r]);
    }
}

// ---------------- combine: carry chunk states (in-place hend -> h_init) -----
__global__ __launch_bounds__(256) void k_comb(unsigned short* __restrict__ hh,
                                              const float* __restrict__ cumA){
  int bh = blockIdx.x, tid = threadIdx.x;
  float carry[16];
  #pragma unroll
  for (int i = 0; i < 16; ++i) carry[i] = 0.f;
  #pragma unroll
  for (int c = 0; c < NCHUNK; ++c){
    size_t base = (((size_t)bh*NCHUNK + c) << 12) + tid*16;
    bf16x8 a0 = *(const bf16x8*)(hh + base);
    bf16x8 a1 = *(const bf16x8*)(hh + base + 8);
    float ca = cumA[bh*NCHUNK + c];
    float tmp[16];
    #pragma unroll
    for (int i = 0; i < 8; ++i){
      tmp[i]   = bf2f((unsigned short)a0[i]);
      tmp[8+i] = bf2f((unsigned short)a1[i]);
    }
    bf16x8 w0, w1;
    #pragma unroll
    for (int i = 0; i < 8; ++i){
      w0[i] = (short)f2bf(carry[i]);
      w1[i] = (short)f2bf(carry[8+i]);
    }
    *(bf16x8*)(hh + base)     = w0;
    *(bf16x8*)(hh + base + 8) = w1;
    #pragma unroll
    for (int i = 0; i < 16; ++i) carry[i] = tmp[i] + ca*carry[i];
  }
}

// ---------------- SSD pass 2 (conv fused): Y = G·X + diag(a)(C·h_init) ------
__global__ __launch_bounds__(256) void k_ssd2(const unsigned short* __restrict__ zx,
                                              const float* __restrict__ conv_w,
                                              const float* __restrict__ conv_b,
                                              const float* __restrict__ dtb,
                                              const float* __restrict__ csb,
                                              const float* __restrict__ A_log,
                                              const float* __restrict__ Dskip,
                                              const unsigned short* __restrict__ hbuf,
                                              unsigned short* __restrict__ yb){
  __shared__ __align__(16) unsigned short Bl[128*72];
  __shared__ __align__(16) unsigned short Cl[128*72];
  __shared__ __align__(16) unsigned short XTl[64*136];
  __shared__ __align__(16) unsigned short hl[64*72];
  __shared__ __align__(16) unsigned short Gm[128*136];
  __shared__ float cs_l[128], dt_l[128], a_l[128];

  int id = blockIdx.x;
  int bh = id >> 3, c = id & 7;
  int b  = bh >> 5, h = bh & 31;
  int tid = threadIdx.x;
  int w = tid >> 6, l = tid & 63;
  float A = -expf(A_log[h]);
  int row0 = b*SEQ + (c << 7);

  // stage B and C (conv fused); group g: 0-7 -> B, 8-15 -> C
  {
    int g = tid & 15, trow = tid >> 4;
    int cc = (g < 8) ? (2048 + g*8) : (2112 + (g-8)*8);
    unsigned short* dst0 = (g < 8) ? (Bl + g*8) : (Cl + (g-8)*8);
    #pragma unroll
    for (int it = 0; it < 8; ++it){
      int tau = trow + it*16;
      float o[8];
      conv8(zx, conv_w, conv_b, b, (c << 7) + tau, cc, o);
      bf16x8 v;
      #pragma unroll
      for (int j = 0; j < 8; ++j) v[j] = (short)f2bf(o[j]);
      *(bf16x8*)(dst0 + tau*72) = v;
    }
  }
  // stage X^T (conv fused)
  {
    int pb = tid & 7, trow = tid >> 3;
    int cc = h*64 + pb*8;
    #pragma unroll
    for (int it = 0; it < 4; ++it){
      int tau = trow + it*32;
      float o[8];
      conv8(zx, conv_w, conv_b, b, (c << 7) + tau, cc, o);
      #pragma unroll
      for (int j = 0; j < 8; ++j)
        XTl[(pb*8+j)*136 + tau] = f2bf(o[j]);
    }
  }
  // stage h_init [p][s]
  #pragma unroll
  for (int it = 0; it < 2; ++it){
    int idx = it*256 + tid;
    int p = idx >> 3, sb = idx & 7;
    bf16x8 v = *(const bf16x8*)(hbuf + (size_t)id*4096 + p*64 + sb*8);
    *(bf16x8*)(hl + p*72 + sb*8) = v;
  }
  if (tid < 128){
    float cs = csb[(size_t)id*128 + tid];
    cs_l[tid] = cs;
    dt_l[tid] = dtb[(size_t)bh*1024 + (c<<7) + tid];
    a_l[tid]  = expf(A*cs);
  }
  __syncthreads();

  int fr = l & 15, fo = (l >> 4) << 3;
  int mtB = 7 - w;

  // Step A: Y = C·h_init, scale rows by a[t]
  f32x4 Y[2][4];
  #pragma unroll
  for (int mi = 0; mi < 2; ++mi)
    #pragma unroll
    for (int n = 0; n < 4; ++n) Y[mi][n] = (f32x4){0.f,0.f,0.f,0.f};
  #pragma unroll
  for (int mi = 0; mi < 2; ++mi){
    int mt = mi ? mtB : w;
    #pragma unroll
    for (int kt = 0; kt < 2; ++kt){
      bf16x8 pf = *(const bf16x8*)(Cl + (mt*16+fr)*72 + kt*32 + fo);
      #pragma unroll
      for (int n = 0; n < 4; ++n){
        bf16x8 qf = *(const bf16x8*)(hl + (n*16+fr)*72 + kt*32 + fo);
        Y[mi][n] = __builtin_amdgcn_mfma_f32_16x16x32_bf16(pf, qf, Y[mi][n], 0, 0, 0);
      }
    }
    #pragma unroll
    for (int r = 0; r < 4; ++r){
      float av = a_l[mt*16 + ((l>>4)<<2) + r];
      #pragma unroll
      for (int n = 0; n < 4; ++n) Y[mi][n][r] *= av;
    }
  }

  // Step B: S = C·B^T on lower-triangular tiles; mask+scale in regs
  f32x4 Sv[9];
  #pragma unroll
  for (int slot = 0; slot < 9; ++slot){
    int mt = (slot <= w) ? w : mtB;
    int nt = (slot <= w) ? slot : slot - w - 1;
    f32x4 acc = (f32x4){0.f,0.f,0.f,0.f};
    #pragma unroll
    for (int kt = 0; kt < 2; ++kt){
      bf16x8 pf = *(const bf16x8*)(Cl + (mt*16+fr)*72 + kt*32 + fo);
      bf16x8 qf = *(const bf16x8*)(Bl + (nt*16+fr)*72 + kt*32 + fo);
      acc = __builtin_amdgcn_mfma_f32_16x16x32_bf16(pf, qf, acc, 0, 0, 0);
    }
    int tau = nt*16 + fr;
    float dtt = dt_l[tau];
    float cst = cs_l[tau];
    #pragma unroll
    for (int r = 0; r < 4; ++r){
      int t = mt*16 + ((l>>4)<<2) + r;
      float v = acc[r] * dtt * expf(A*(cs_l[t] - cst));
      acc[r] = (tau <= t) ? v : 0.f;
    }
    Sv[slot] = acc;
  }

  __syncthreads();

  #pragma unroll
  for (int slot = 0; slot < 9; ++slot){
    int mt = (slot <= w) ? w : mtB;
    int nt = (slot <= w) ? slot : slot - w - 1;
    int tau = nt*16 + fr;
    #pragma unroll
    for (int r = 0; r < 4; ++r){
      int t = mt*16 + ((l>>4)<<2) + r;
      Gm[t*136 + tau] = f2bf(Sv[slot][r]);
    }
  }
  { // zero-fill diagonal-adjacent tile of the even m-tile
    int mtE = (w & 1) ? mtB : w;
    int ntE = mtE + 1;
    #pragma unroll
    for (int r = 0; r < 4; ++r){
      int t = mtE*16 + ((l>>4)<<2) + r;
      Gm[t*136 + ntE*16 + fr] = 0;
    }
  }
  __syncthreads();

  // Step C: Y += G·X (k only up to diagonal)
  #pragma unroll
  for (int mi = 0; mi < 2; ++mi){
    int mt = mi ? mtB : w;
    int kmax = (mt + 2) >> 1;
    for (int kt2 = 0; kt2 < kmax; ++kt2){
      bf16x8 pf = *(const bf16x8*)(Gm + (mt*16+fr)*136 + kt2*32 + fo);
      #pragma unroll
      for (int n = 0; n < 4; ++n){
        bf16x8 qf = *(const bf16x8*)(XTl + (n*16+fr)*136 + kt2*32 + fo);
        Y[mi][n] = __builtin_amdgcn_mfma_f32_16x16x32_bf16(pf, qf, Y[mi][n], 0, 0, 0);
      }
    }
  }

  // output: y = Y + Dskip * x
  float dsk = Dskip[h];
  #pragma unroll
  for (int mi = 0; mi < 2; ++mi){
    int mt = mi ? mtB : w;
    #pragma unroll
    for (int r = 0; r < 4; ++r){
      int t = mt*16 + ((l>>4)<<2) + r;
      size_t orow = (size_t)(row0 + t)*D_INNER + h*64;
      #pragma unroll
      for (int n = 0; n < 4; ++n){
        int p = n*16 + fr;
        float xv = bf2f(XTl[p*136 + t]);
        yb[orow + p] = f2bf(Y[mi][n][r] + dsk*xv);
      }
    }
  }
}

// ---------------- fused gate + RMS + (norm_w*W_out@head_w) dot --------------
__global__ __launch_bounds__(256) void k_epilogue(const unsigned short* __restrict__ y,
                                                  const unsigned short* __restrict__ zx,
                                                  const float* __restrict__ nwc,
                                                  const float* __restrict__ head_b,
                                                  float* __restrict__ out){
  int r   = blockIdx.x;
  int tid = threadIdx.x;
  bf16x8 y8 = *(const bf16x8*)(y  + (size_t)r*D_INNER + tid*8);
  bf16x8 z8 = *(const bf16x8*)(zx + (size_t)r*NPAD   + tid*8);
  float4 w0 = ((const float4*)nwc)[tid*2];
  float4 w1 = ((const float4*)nwc)[tid*2 + 1];
  float wv[8] = {w0.x, w0.y, w0.z, w0.w, w1.x, w1.y, w1.z, w1.w};
  float s2 = 0.f, sd = 0.f;
  #pragma unroll
  for (int k = 0; k < 8; ++k){
    float yf = bf2f((unsigned short)y8[k]);
    float zf = bf2f((unsigned short)z8[k]);
    float g  = yf * (zf / (1.f + expf(-zf)));
    s2 += g*g; sd += g*wv[k];
  }
  #pragma unroll
  for (int off = 32; off; off >>= 1){
    s2 += __shfl_down(s2, off);
    sd += __shfl_down(sd, off);
  }
  __shared__ float r2[4], rd[4];
  if ((tid & 63) == 0){ r2[tid >> 6] = s2; rd[tid >> 6] = sd; }
  __syncthreads();
  if (tid == 0){
    float t2 = r2[0] + r2[1] + r2[2] + r2[3];
    float td = rd[0] + rd[1] + rd[2] + rd[3];
    out[r] = rsqrtf(t2 * (1.f/2048.f) + 1e-5f) * td + head_b[0];
  }
}

extern "C" void kernel_launch(void* const* d_in, const int* in_sizes, int n_in,
                              void* d_out, int out_size, void* d_ws, size_t ws_size,
                              hipStream_t stream){
  const float* x       = (const float*)d_in[0];
  const float* W_in    = (const float*)d_in[1];
  const float* conv_w  = (const float*)d_in[2];
  const float* conv_b  = (const float*)d_in[3];
  const float* dt_bias = (const float*)d_in[4];
  const float* A_log   = (const float*)d_in[5];
  const float* Dskip   = (const float*)d_in[6];
  const float* norm_w  = (const float*)d_in[7];
  const float* W_out   = (const float*)d_in[8];
  const float* head_w  = (const float*)d_in[9];
  const float* head_b  = (const float*)d_in[10];
  float* out = (float*)d_out;

  char* ws = (char*)d_ws;
  unsigned short* xb   = (unsigned short*)(ws + 0);            // 16,777,216 (reused: hbuf)
  unsigned short* wt   = (unsigned short*)(ws + 16777216);     //  8,912,896 W_in^T (reused: csb|cumA)
  unsigned short* zx16 = (unsigned short*)(ws + 25690112);     // 71,303,168
  float*          dtb  = (float*)         (ws + 132644864);    //  1,048,576
  float*          nwc  = (float*)         (ws + 134742016);    //      8,192
  unsigned short* yb   = (unsigned short*)(ws + 134750208);    // 33,554,432

  unsigned short* hbuf = xb;                                   // 2048*4096*2B
  float*          csb  = (float*)(ws + 16777216 + 2097152);    // 2048*128*4B
  float*          cumA = (float*)(ws + 16777216 + 3145728);    // 8,192

  k_convert_x<<<8192, 256, 0, stream>>>(x, xb);
  k_transpose_win<<<dim3(136, 32), 256, 0, stream>>>(W_in, wt);
  k_nwc<<<512, 256, 0, stream>>>(W_out, head_w, norm_w, nwc);
  k_gemm_bf16_bt<<<(NROWS/128)*(NPAD/128), 256, 0, stream>>>(xb, wt, zx16, NROWS, NPAD, D_MODEL);
  k_dtda<<<1024, 256, 0, stream>>>(zx16, dt_bias, dtb);
  k_cs<<<2048, 64, 0, stream>>>(dtb, A_log, csb, cumA);
  k_ssd1<<<2048, 256, 0, stream>>>(zx16, conv_w, conv_b, dtb, csb, A_log, hbuf);
  k_comb<<<256, 256, 0, stream>>>(hbuf, cumA);
  k_ssd2<<<2048, 256, 0, stream>>>(zx16, conv_w, conv_b, dtb, csb, A_log, Dskip, hbuf, yb);
  k_epilogue<<<NROWS, 256, 0, stream>>>(yb, zx16, nwc, head_b, out);
}

// Round 8
// 280.425 us; speedup vs baseline: 1.3059x; 1.3059x over previous
//
#include <hip/hip_runtime.h>
#include <hip/hip_bf16.h>

#define D_MODEL   1024
#define D_STATE   64
#define D_INNER   2048
#define NHEADS    32
#define CONV_DIM  2176
#define D_IN_PROJ 4256
#define NPAD      4352
#define BATCH     8
#define SEQ       1024
#define NROWS     8192
#define NCHUNK    8
#define CLEN      128

typedef __attribute__((ext_vector_type(8))) short bf16x8;
typedef __attribute__((ext_vector_type(4))) float f32x4;

__device__ __forceinline__ float bf2f(unsigned short u){
  unsigned v = ((unsigned)u) << 16;
  return __builtin_bit_cast(float, v);
}
__device__ __forceinline__ unsigned short f2bf(float f){
  __hip_bfloat16 h = __float2bfloat16(f);
  return __builtin_bit_cast(unsigned short, h);
}

// ---------------- convert x (fp32 -> bf16) ----------------
__global__ __launch_bounds__(256) void k_convert_x(const float* __restrict__ x,
                                                   unsigned short* __restrict__ xb){
  int i = blockIdx.x*256 + threadIdx.x;
  float4 v = ((const float4*)x)[i];
  ushort4 o;
  o.x = f2bf(v.x); o.y = f2bf(v.y); o.z = f2bf(v.z); o.w = f2bf(v.w);
  ((ushort4*)xb)[i] = o;
}

// ---------------- transpose W_in [K][N] -> bf16 [NPAD][K] -------------------
__global__ __launch_bounds__(256) void k_transpose_win(const float* __restrict__ W_in,
                                                       unsigned short* __restrict__ wt){
  __shared__ float tile[32][33];
  int n0 = blockIdx.x * 32;
  int k0 = blockIdx.y * 32;
  int tx = threadIdx.x & 31;
  int ty = threadIdx.x >> 5;
  #pragma unroll
  for (int i = 0; i < 4; ++i){
    int kk = ty + i*8;
    int n  = n0 + tx;
    tile[kk][tx] = (n < D_IN_PROJ) ? W_in[(size_t)(k0+kk)*D_IN_PROJ + n] : 0.f;
  }
  __syncthreads();
  #pragma unroll
  for (int i = 0; i < 4; ++i){
    int nn = ty + i*8;
    wt[(size_t)(n0+nn)*D_MODEL + k0 + tx] = f2bf(tile[tx][nn]);
  }
}

// ---------------- nwc[d] = norm_w[d] * sum_k W_out[d][k]*head_w[k] ----------
__global__ __launch_bounds__(256) void k_nwc(const float* __restrict__ W_out,
                                             const float* __restrict__ head_w,
                                             const float* __restrict__ norm_w,
                                             float* __restrict__ nwc){
  int d    = blockIdx.x*4 + (threadIdx.x >> 6);
  int lane = threadIdx.x & 63;
  const float* row = W_out + (size_t)d * D_MODEL;
  float s = 0.f;
  #pragma unroll
  for (int k = lane; k < D_MODEL; k += 64) s += row[k] * head_w[k];
  #pragma unroll
  for (int off = 32; off; off >>= 1) s += __shfl_down(s, off);
  if (lane == 0) nwc[d] = s * norm_w[d];
}

// ---------------- bf16 MFMA GEMM with XCD-aware block swizzle ---------------
__global__ __launch_bounds__(256) void k_gemm_bf16_bt(const unsigned short* __restrict__ A,
                                                      const unsigned short* __restrict__ BT,
                                                      unsigned short* __restrict__ C,
                                                      int M, int N, int K){
  __shared__ unsigned short aT[128*64];
  __shared__ unsigned short bT[128*64];
  int nb   = N >> 7;
  int bid  = blockIdx.x;
  int swz  = (bid & 7) * (gridDim.x >> 3) + (bid >> 3);
  int m0   = (swz / nb) << 7;
  int n0   = (swz % nb) << 7;
  int tid  = threadIdx.x;
  int wid  = tid >> 6, lane = tid & 63;
  int wr   = wid >> 1, wc = wid & 1;

  f32x4 acc[4][4];
  #pragma unroll
  for (int i = 0; i < 4; ++i)
    #pragma unroll
    for (int j = 0; j < 4; ++j)
      acc[i][j] = (f32x4){0.f, 0.f, 0.f, 0.f};

  int frow = lane & 15;
  int fk   = (lane >> 4) << 3;
  int srow = lane >> 3;
  int skk  = (lane & 7) << 3;

  for (int k0 = 0; k0 < K; k0 += 64){
    __syncthreads();
    #pragma unroll
    for (int it = 0; it < 4; ++it){
      int ch  = (wid << 2) | it;
      int row = (ch << 3) | srow;
      __builtin_amdgcn_global_load_lds(
        (const __attribute__((address_space(1))) void*)(A  + (size_t)(m0+row)*K + k0 + skk),
        (__attribute__((address_space(3))) void*)(aT + (ch << 9)), 16, 0, 0);
      __builtin_amdgcn_global_load_lds(
        (const __attribute__((address_space(1))) void*)(BT + (size_t)(n0+row)*K + k0 + skk),
        (__attribute__((address_space(3))) void*)(bT + (ch << 9)), 16, 0, 0);
    }
    __syncthreads();
    #pragma unroll
    for (int kk = 0; kk < 64; kk += 32){
      bf16x8 af[4], bfv[4];
      #pragma unroll
      for (int i = 0; i < 4; ++i)
        af[i]  = *(const bf16x8*)(aT + ((wr*64 + i*16 + frow) << 6) + kk + fk);
      #pragma unroll
      for (int j = 0; j < 4; ++j)
        bfv[j] = *(const bf16x8*)(bT + ((wc*64 + j*16 + frow) << 6) + kk + fk);
      #pragma unroll
      for (int i = 0; i < 4; ++i)
        #pragma unroll
        for (int j = 0; j < 4; ++j)
          acc[i][j] = __builtin_amdgcn_mfma_f32_16x16x32_bf16(af[i], bfv[j], acc[i][j], 0, 0, 0);
    }
  }

  int crow = (lane >> 4) << 2;
  int ccol = lane & 15;
  #pragma unroll
  for (int i = 0; i < 4; ++i)
    #pragma unroll
    for (int j = 0; j < 4; ++j){
      size_t base = (size_t)(m0 + wr*64 + i*16 + crow) * N + (n0 + wc*64 + j*16 + ccol);
      #pragma unroll
      for (int r = 0; r < 4; ++r)
        C[base + (size_t)r * N] = f2bf(acc[i][j][r]);
    }
}

// ---------------- dt = softplus(raw + bias), transposed [bh][t] -------------
__global__ __launch_bounds__(256) void k_dtda(const unsigned short* __restrict__ zx,
                                              const float* __restrict__ dt_bias,
                                              float* __restrict__ dtb){
  int i = blockIdx.x*256 + threadIdx.x;
  int r = i >> 5, h = i & 31;
  float raw = bf2f(zx[(size_t)r*NPAD + D_INNER + CONV_DIM + h]) + dt_bias[h];
  float dt  = (raw > 20.f) ? raw : log1pf(expf(raw));
  int b = r >> 10, l = r & 1023;
  dtb[(b*32 + h)*1024 + l] = dt;
}

// ---------------- causal conv1d (4 taps) + SiLU, vectorized x8 --------------
// one block per row r; thread handles 8-channel octet(s)
__global__ __launch_bounds__(256) void k_conv(const unsigned short* __restrict__ zx,
                                              const float* __restrict__ conv_w,
                                              const float* __restrict__ conv_b,
                                              unsigned short* __restrict__ xbc,
                                              unsigned short* __restrict__ bc16){
  int r = blockIdx.x;
  int l = r & (SEQ - 1);
  for (int oc = threadIdx.x; oc < 272; oc += 256){
    int c = oc * 8;
    float acc[8];
    #pragma unroll
    for (int j = 0; j < 8; ++j) acc[j] = conv_b[c + j];
    #pragma unroll
    for (int k = 0; k < 4; ++k){
      int dl = l + k - 3;
      if (dl >= 0){
        bf16x8 v = *(const bf16x8*)(zx + (size_t)(r + k - 3)*NPAD + D_INNER + c);
        #pragma unroll
        for (int j = 0; j < 8; ++j)
          acc[j] = fmaf(bf2f((unsigned short)v[j]), conv_w[k*CONV_DIM + c + j], acc[j]);
      }
    }
    bf16x8 o;
    #pragma unroll
    for (int j = 0; j < 8; ++j){
      float s = acc[j] / (1.f + expf(-acc[j]));
      o[j] = (short)f2bf(s);
    }
    if (c < D_INNER) *(bf16x8*)(xbc  + (size_t)r*D_INNER + c) = o;
    else             *(bf16x8*)(bc16 + (size_t)r*128 + (c - D_INNER)) = o;
  }
}

// ---------------- per-chunk inclusive cumsum of dt + cumA -------------------
__global__ __launch_bounds__(64) void k_cs(const float* __restrict__ dtb,
                                           const float* __restrict__ A_log,
                                           float* __restrict__ csb,
                                           float* __restrict__ cumA){
  int id = blockIdx.x;                 // bh*8 + c
  int bh = id >> 3, c = id & 7;
  int h  = bh & 31;
  int l  = threadIdx.x;
  const float* src = dtb + (size_t)bh*1024 + (c << 7);
  float d0 = src[2*l], d1 = src[2*l + 1];
  float pr = d0 + d1;
  float s  = pr;
  #pragma unroll
  for (int off = 1; off < 64; off <<= 1){
    float n = __shfl_up(s, off);
    if (l >= off) s += n;
  }
  float excl = s - pr;
  csb[(size_t)id*128 + 2*l]     = excl + d0;
  csb[(size_t)id*128 + 2*l + 1] = excl + pr;
  if (l == 63){
    float A = -expf(A_log[h]);
    cumA[id] = expf(A * s);
  }
}

// ---------------- SSD pass 1: h_end_local[p][s] = (w*X)^T @ B ---------------
__global__ __launch_bounds__(256) void k_ssd1(const unsigned short* __restrict__ xbc,
                                              const unsigned short* __restrict__ bc16,
                                              const float* __restrict__ dtb,
                                              const float* __restrict__ csb,
                                              const float* __restrict__ A_log,
                                              unsigned short* __restrict__ hend){
  __shared__ __align__(16) unsigned short XTw[64*136];
  __shared__ __align__(16) unsigned short BTl[64*136];
  int id = blockIdx.x;
  int bh = id >> 3, c = id & 7;
  int b  = bh >> 5, h = bh & 31;
  int tid = threadIdx.x;
  int w = tid >> 6, l = tid & 63;
  float A = -expf(A_log[h]);
  int row0 = b*SEQ + (c << 7);
  float csT = csb[(size_t)id*128 + 127];

  #pragma unroll
  for (int it = 0; it < 4; ++it){
    int idx = it*256 + tid;
    int tau = idx >> 3, pb = idx & 7;
    bf16x8 v = *(const bf16x8*)(xbc + (size_t)(row0+tau)*D_INNER + h*64 + pb*8);
    float wgt = dtb[(size_t)bh*1024 + (c<<7) + tau]
              * expf(A*(csT - csb[(size_t)id*128 + tau]));
    #pragma unroll
    for (int j = 0; j < 8; ++j)
      XTw[(pb*8+j)*136 + tau] = f2bf(bf2f((unsigned short)v[j]) * wgt);
  }
  #pragma unroll
  for (int it = 0; it < 4; ++it){
    int idx = it*256 + tid;
    int tau = idx >> 3, sb = idx & 7;
    bf16x8 v = *(const bf16x8*)(bc16 + (size_t)(row0+tau)*128 + sb*8);
    #pragma unroll
    for (int j = 0; j < 8; ++j)
      BTl[(sb*8+j)*136 + tau] = (unsigned short)v[j];
  }
  __syncthreads();

  int fr = l & 15, fo = (l >> 4) << 3;
  f32x4 acc[4];
  #pragma unroll
  for (int n = 0; n < 4; ++n) acc[n] = (f32x4){0.f,0.f,0.f,0.f};
  #pragma unroll
  for (int kt = 0; kt < 4; ++kt){
    bf16x8 pf = *(const bf16x8*)(XTw + (w*16+fr)*136 + kt*32 + fo);
    #pragma unroll
    for (int n = 0; n < 4; ++n){
      bf16x8 qf = *(const bf16x8*)(BTl + (n*16+fr)*136 + kt*32 + fo);
      acc[n] = __builtin_amdgcn_mfma_f32_16x16x32_bf16(pf, qf, acc[n], 0, 0, 0);
    }
  }
  #pragma unroll
  for (int n = 0; n < 4; ++n)
    #pragma unroll
    for (int r = 0; r < 4; ++r){
      int p = w*16 + ((l>>4)<<2) + r;
      int s = n*16 + fr;
      hend[(size_t)id*4096 + p*64 + s] = f2bf(acc[n][r]);
    }
}

// ---------------- combine: carry chunk states (in-place hend -> h_init) -----
__global__ __launch_bounds__(256) void k_comb(unsigned short* __restrict__ hh,
                                              const float* __restrict__ cumA){
  int bh = blockIdx.x, tid = threadIdx.x;
  float carry[16];
  #pragma unroll
  for (int i = 0; i < 16; ++i) carry[i] = 0.f;
  #pragma unroll
  for (int c = 0; c < NCHUNK; ++c){
    size_t base = (((size_t)bh*NCHUNK + c) << 12) + tid*16;
    bf16x8 a0 = *(const bf16x8*)(hh + base);
    bf16x8 a1 = *(const bf16x8*)(hh + base + 8);
    float ca = cumA[bh*NCHUNK + c];
    float tmp[16];
    #pragma unroll
    for (int i = 0; i < 8; ++i){
      tmp[i]   = bf2f((unsigned short)a0[i]);
      tmp[8+i] = bf2f((unsigned short)a1[i]);
    }
    bf16x8 w0, w1;
    #pragma unroll
    for (int i = 0; i < 8; ++i){
      w0[i] = (short)f2bf(carry[i]);
      w1[i] = (short)f2bf(carry[8+i]);
    }
    *(bf16x8*)(hh + base)     = w0;
    *(bf16x8*)(hh + base + 8) = w1;
    #pragma unroll
    for (int i = 0; i < 16; ++i) carry[i] = tmp[i] + ca*carry[i];
  }
}

// ---------------- SSD pass 2: Y = (mask.(C B^T)) X + diag(a) (C h_init) -----
__global__ __launch_bounds__(256) void k_ssd2(const unsigned short* __restrict__ xbc,
                                              const unsigned short* __restrict__ bc16,
                                              const float* __restrict__ dtb,
                                              const float* __restrict__ csb,
                                              const float* __restrict__ A_log,
                                              const float* __restrict__ Dskip,
                                              const unsigned short* __restrict__ hbuf,
                                              unsigned short* __restrict__ yb){
  __shared__ __align__(16) unsigned short Bl[128*72];
  __shared__ __align__(16) unsigned short Cl[128*72];
  __shared__ __align__(16) unsigned short XTl[64*136];
  __shared__ __align__(16) unsigned short hl[64*72];
  __shared__ __align__(16) unsigned short Gm[128*136];
  __shared__ float cs_l[128], dt_l[128], a_l[128];

  int id = blockIdx.x;
  int bh = id >> 3, c = id & 7;
  int b  = bh >> 5, h = bh & 31;
  int tid = threadIdx.x;
  int w = tid >> 6, l = tid & 63;
  float A = -expf(A_log[h]);
  int row0 = b*SEQ + (c << 7);

  // stage B and C
  #pragma unroll
  for (int it = 0; it < 8; ++it){
    int idx = it*256 + tid;
    int tau = idx >> 4, cb = idx & 15;
    bf16x8 v = *(const bf16x8*)(bc16 + (size_t)(row0+tau)*128 + cb*8);
    unsigned short* dst = (cb < 8) ? (Bl + tau*72 + cb*8)
                                   : (Cl + tau*72 + (cb-8)*8);
    *(bf16x8*)dst = v;
  }
  // stage X^T
  #pragma unroll
  for (int it = 0; it < 4; ++it){
    int idx = it*256 + tid;
    int tau = idx >> 3, pb = idx & 7;
    bf16x8 v = *(const bf16x8*)(xbc + (size_t)(row0+tau)*D_INNER + h*64 + pb*8);
    #pragma unroll
    for (int j = 0; j < 8; ++j)
      XTl[(pb*8+j)*136 + tau] = (unsigned short)v[j];
  }
  // stage h_init [p][s]
  #pragma unroll
  for (int it = 0; it < 2; ++it){
    int idx = it*256 + tid;
    int p = idx >> 3, sb = idx & 7;
    bf16x8 v = *(const bf16x8*)(hbuf + (size_t)id*4096 + p*64 + sb*8);
    *(bf16x8*)(hl + p*72 + sb*8) = v;
  }
  if (tid < 128){
    float cs = csb[(size_t)id*128 + tid];
    cs_l[tid] = cs;
    dt_l[tid] = dtb[(size_t)bh*1024 + (c<<7) + tid];
    a_l[tid]  = expf(A*cs);
  }
  __syncthreads();

  int fr = l & 15, fo = (l >> 4) << 3;
  int mtB = 7 - w;

  // Step A: Y = C·h_init, scale rows by a[t]
  f32x4 Y[2][4];
  #pragma unroll
  for (int mi = 0; mi < 2; ++mi)
    #pragma unroll
    for (int n = 0; n < 4; ++n) Y[mi][n] = (f32x4){0.f,0.f,0.f,0.f};
  #pragma unroll
  for (int mi = 0; mi < 2; ++mi){
    int mt = mi ? mtB : w;
    #pragma unroll
    for (int kt = 0; kt < 2; ++kt){
      bf16x8 pf = *(const bf16x8*)(Cl + (mt*16+fr)*72 + kt*32 + fo);
      #pragma unroll
      for (int n = 0; n < 4; ++n){
        bf16x8 qf = *(const bf16x8*)(hl + (n*16+fr)*72 + kt*32 + fo);
        Y[mi][n] = __builtin_amdgcn_mfma_f32_16x16x32_bf16(pf, qf, Y[mi][n], 0, 0, 0);
      }
    }
    #pragma unroll
    for (int r = 0; r < 4; ++r){
      float av = a_l[mt*16 + ((l>>4)<<2) + r];
      #pragma unroll
      for (int n = 0; n < 4; ++n) Y[mi][n][r] *= av;
    }
  }

  // Step B: S = C·B^T on lower-triangular tiles; mask+scale in regs
  f32x4 Sv[9];
  #pragma unroll
  for (int slot = 0; slot < 9; ++slot){
    int mt = (slot <= w) ? w : mtB;
    int nt = (slot <= w) ? slot : slot - w - 1;
    f32x4 acc = (f32x4){0.f,0.f,0.f,0.f};
    #pragma unroll
    for (int kt = 0; kt < 2; ++kt){
      bf16x8 pf = *(const bf16x8*)(Cl + (mt*16+fr)*72 + kt*32 + fo);
      bf16x8 qf = *(const bf16x8*)(Bl + (nt*16+fr)*72 + kt*32 + fo);
      acc = __builtin_amdgcn_mfma_f32_16x16x32_bf16(pf, qf, acc, 0, 0, 0);
    }
    int tau = nt*16 + fr;
    float dtt = dt_l[tau];
    float cst = cs_l[tau];
    #pragma unroll
    for (int r = 0; r < 4; ++r){
      int t = mt*16 + ((l>>4)<<2) + r;
      float v = acc[r] * dtt * expf(A*(cs_l[t] - cst));
      acc[r] = (tau <= t) ? v : 0.f;
    }
    Sv[slot] = acc;
  }

  __syncthreads();

  #pragma unroll
  for (int slot = 0; slot < 9; ++slot){
    int mt = (slot <= w) ? w : mtB;
    int nt = (slot <= w) ? slot : slot - w - 1;
    int tau = nt*16 + fr;
    #pragma unroll
    for (int r = 0; r < 4; ++r){
      int t = mt*16 + ((l>>4)<<2) + r;
      Gm[t*136 + tau] = f2bf(Sv[slot][r]);
    }
  }
  { // zero-fill diagonal-adjacent tile of the even m-tile
    int mtE = (w & 1) ? mtB : w;
    int ntE = mtE + 1;
    #pragma unroll
    for (int r = 0; r < 4; ++r){
      int t = mtE*16 + ((l>>4)<<2) + r;
      Gm[t*136 + ntE*16 + fr] = 0;
    }
  }
  __syncthreads();

  // Step C: Y += G·X (k only up to diagonal)
  #pragma unroll
  for (int mi = 0; mi < 2; ++mi){
    int mt = mi ? mtB : w;
    int kmax = (mt + 2) >> 1;
    for (int kt2 = 0; kt2 < kmax; ++kt2){
      bf16x8 pf = *(const bf16x8*)(Gm + (mt*16+fr)*136 + kt2*32 + fo);
      #pragma unroll
      for (int n = 0; n < 4; ++n){
        bf16x8 qf = *(const bf16x8*)(XTl + (n*16+fr)*136 + kt2*32 + fo);
        Y[mi][n] = __builtin_amdgcn_mfma_f32_16x16x32_bf16(pf, qf, Y[mi][n], 0, 0, 0);
      }
    }
  }

  // output: y = Y + Dskip * x
  float dsk = Dskip[h];
  #pragma unroll
  for (int mi = 0; mi < 2; ++mi){
    int mt = mi ? mtB : w;
    #pragma unroll
    for (int r = 0; r < 4; ++r){
      int t = mt*16 + ((l>>4)<<2) + r;
      size_t orow = (size_t)(row0 + t)*D_INNER + h*64;
      #pragma unroll
      for (int n = 0; n < 4; ++n){
        int p = n*16 + fr;
        float xv = bf2f(XTl[p*136 + t]);
        yb[orow + p] = f2bf(Y[mi][n][r] + dsk*xv);
      }
    }
  }
}

// ---------------- fused gate + RMS + (norm_w*W_out@head_w) dot --------------
__global__ __launch_bounds__(256) void k_epilogue(const unsigned short* __restrict__ y,
                                                  const unsigned short* __restrict__ zx,
                                                  const float* __restrict__ nwc,
                                                  const float* __restrict__ head_b,
                                                  float* __restrict__ out){
  int r   = blockIdx.x;
  int tid = threadIdx.x;
  bf16x8 y8 = *(const bf16x8*)(y  + (size_t)r*D_INNER + tid*8);
  bf16x8 z8 = *(const bf16x8*)(zx + (size_t)r*NPAD   + tid*8);
  float4 w0 = ((const float4*)nwc)[tid*2];
  float4 w1 = ((const float4*)nwc)[tid*2 + 1];
  float wv[8] = {w0.x, w0.y, w0.z, w0.w, w1.x, w1.y, w1.z, w1.w};
  float s2 = 0.f, sd = 0.f;
  #pragma unroll
  for (int k = 0; k < 8; ++k){
    float yf = bf2f((unsigned short)y8[k]);
    float zf = bf2f((unsigned short)z8[k]);
    float g  = yf * (zf / (1.f + expf(-zf)));
    s2 += g*g; sd += g*wv[k];
  }
  #pragma unroll
  for (int off = 32; off; off >>= 1){
    s2 += __shfl_down(s2, off);
    sd += __shfl_down(sd, off);
  }
  __shared__ float r2[4], rd[4];
  if ((tid & 63) == 0){ r2[tid >> 6] = s2; rd[tid >> 6] = sd; }
  __syncthreads();
  if (tid == 0){
    float t2 = r2[0] + r2[1] + r2[2] + r2[3];
    float td = rd[0] + rd[1] + rd[2] + rd[3];
    out[r] = rsqrtf(t2 * (1.f/2048.f) + 1e-5f) * td + head_b[0];
  }
}

extern "C" void kernel_launch(void* const* d_in, const int* in_sizes, int n_in,
                              void* d_out, int out_size, void* d_ws, size_t ws_size,
                              hipStream_t stream){
  const float* x       = (const float*)d_in[0];
  const float* W_in    = (const float*)d_in[1];
  const float* conv_w  = (const float*)d_in[2];
  const float* conv_b  = (const float*)d_in[3];
  const float* dt_bias = (const float*)d_in[4];
  const float* A_log   = (const float*)d_in[5];
  const float* Dskip   = (const float*)d_in[6];
  const float* norm_w  = (const float*)d_in[7];
  const float* W_out   = (const float*)d_in[8];
  const float* head_w  = (const float*)d_in[9];
  const float* head_b  = (const float*)d_in[10];
  float* out = (float*)d_out;

  char* ws = (char*)d_ws;
  unsigned short* xb   = (unsigned short*)(ws + 0);            // 16,777,216 (reused: hbuf)
  unsigned short* wt   = (unsigned short*)(ws + 16777216);     //  8,912,896 W_in^T (reused: bc16|csb|cumA)
  unsigned short* zx16 = (unsigned short*)(ws + 25690112);     // 71,303,168
  unsigned short* xbc  = (unsigned short*)(ws + 96993280);     // 33,554,432 ([r][2048] x only)
  float*          dtb  = (float*)         (ws + 132644864);    //  1,048,576
  float*          nwc  = (float*)         (ws + 134742016);    //      8,192
  unsigned short* yb   = (unsigned short*)(ws + 134750208);    // 33,554,432

  unsigned short* hbuf = xb;                                   // 2048*4096*2B
  unsigned short* bc16 = wt;                                   // 8192*128*2B = 2,097,152
  float*          csb  = (float*)(ws + 16777216 + 2097152);    // 2048*128*4B
  float*          cumA = (float*)(ws + 16777216 + 3145728);    // 8,192

  k_convert_x<<<8192, 256, 0, stream>>>(x, xb);
  k_transpose_win<<<dim3(136, 32), 256, 0, stream>>>(W_in, wt);
  k_nwc<<<512, 256, 0, stream>>>(W_out, head_w, norm_w, nwc);
  k_gemm_bf16_bt<<<(NROWS/128)*(NPAD/128), 256, 0, stream>>>(xb, wt, zx16, NROWS, NPAD, D_MODEL);
  k_dtda<<<1024, 256, 0, stream>>>(zx16, dt_bias, dtb);
  k_conv<<<NROWS, 256, 0, stream>>>(zx16, conv_w, conv_b, xbc, bc16);
  k_cs<<<2048, 64, 0, stream>>>(dtb, A_log, csb, cumA);
  k_ssd1<<<2048, 256, 0, stream>>>(xbc, bc16, dtb, csb, A_log, hbuf);
  k_comb<<<256, 256, 0, stream>>>(hbuf, cumA);
  k_ssd2<<<2048, 256, 0, stream>>>(xbc, bc16, dtb, csb, A_log, Dskip, hbuf, yb);
  k_epilogue<<<NROWS, 256, 0, stream>>>(yb, zx16, nwc, head_b, out);
}